// Round 10
// baseline (312.814 us; speedup 1.0000x reference)
//
#include <hip/hip_runtime.h>

typedef _Float16 half8   __attribute__((ext_vector_type(8)));
typedef _Float16 half4_t __attribute__((ext_vector_type(4)));
typedef float    float4_t __attribute__((ext_vector_type(4)));

#define B_   8
#define N_   4096
#define C_   256
#define F_   64

#if defined(__has_builtin) && __has_builtin(__builtin_amdgcn_exp2f)
#define EXP2(x) __builtin_amdgcn_exp2f(x)
#else
#define EXP2(x) exp2f(x)
#endif
#define LOG2E 1.44269504f

static __device__ __forceinline__ float4_t mfma16(half8 a, half8 b, float4_t c) {
  return __builtin_amdgcn_mfma_f32_16x16x32_f16(a, b, c, 0, 0, 0);
}

// DPP cross-lane within 16-lane rows: row_ror:N = 0x120|N.
template <int CTRL>
static __device__ __forceinline__ float dpp_f(float x) {
  return __int_as_float(__builtin_amdgcn_update_dpp(
      __float_as_int(x), __float_as_int(x), CTRL, 0xF, 0xF, false));
}
static __device__ __forceinline__ float row_max16(float v) {
  v = fmaxf(v, dpp_f<0x128>(v));
  v = fmaxf(v, dpp_f<0x124>(v));
  v = fmaxf(v, dpp_f<0x122>(v));
  v = fmaxf(v, dpp_f<0x121>(v));
  return v;
}
static __device__ __forceinline__ float row_sum16(float v) {
  v += dpp_f<0x128>(v);
  v += dpp_f<0x124>(v);
  v += dpp_f<0x122>(v);
  v += dpp_f<0x121>(v);
  return v;
}

// Async global->LDS K staging, pre-swizzled per-lane SOURCE + linear LDS dest
// (HW constraint: dest = wave-uniform base + lane*16B). Swizzle granule (16B)
// == load width, so LDS[row][b] = G[row][b ^ (row&7)] — identical layout to the
// old ds_write path; the swizzled QK read side is unchanged. Verified correct
// in R4 (that round's regression came from two OTHER bundled changes).
static __device__ __forceinline__ void stage_k(const _Float16* gsrc,  // + j0*64
                                               _Float16* kd,          // tile base
                                               int wave, int lane) {
  const int srow = lane >> 3;              // 0..7
  const int sblk = (lane & 7) ^ srow;      // swizzled source 16B-block
  const _Float16* s = gsrc + (size_t)(wave * 16 + srow) * 64 + (sblk << 3);
  _Float16* d = kd + (wave * 16) * 64;     // wave-uniform
  __builtin_amdgcn_global_load_lds(
      (const __attribute__((address_space(1))) unsigned int*)s,
      (__attribute__((address_space(3))) unsigned int*)d, 16, 0, 0);
  s += 8 * 64;
  d += 8 * 64;
  __builtin_amdgcn_global_load_lds(
      (const __attribute__((address_space(1))) unsigned int*)s,
      (__attribute__((address_space(3))) unsigned int*)d, 16, 0, 0);
}

// ------------- fused prep: whvt (blocks 0..255) + wfgt (blocks 256..383) ---------
__global__ __launch_bounds__(256) void prep_kernel(const float* __restrict__ Wh,
                                                   const float* __restrict__ Wv,
                                                   const float* __restrict__ Wf,
                                                   const float* __restrict__ Wg,
                                                   _Float16* __restrict__ whvt,
                                                   _Float16* __restrict__ wfgt) {
  int c = threadIdx.x;
  if (blockIdx.x < 256) {
    int d = blockIdx.x;    // uniform per block -> Wv reads become s_loads
    const float4_t* whr = (const float4_t*)(Wh + (size_t)c * 256);
    float acc = 0.f;
#pragma unroll 8
    for (int e4 = 0; e4 < 64; ++e4) {
      float4_t w4 = whr[e4];
      acc += w4[0] * Wv[(e4 * 4 + 0) * 256 + d];
      acc += w4[1] * Wv[(e4 * 4 + 1) * 256 + d];
      acc += w4[2] * Wv[(e4 * 4 + 2) * 256 + d];
      acc += w4[3] * Wv[(e4 * 4 + 3) * 256 + d];
    }
    whvt[d * 256 + c] = (_Float16)acc;
  } else {
    int n = blockIdx.x - 256;   // 0..127
    float v = (n < 64) ? Wf[c * 64 + n] * LOG2E : Wg[c * 64 + (n - 64)];
    wfgt[n * 256 + c] = (_Float16)v;
  }
}

// ------- fused f,g GEMM + x transpose: reads x ONCE from HBM ---------------------
// Phase A: [32768x256] @ wfgt^T -> f16 f,g (verbatim known-good).
// Phase B: proven shared-tile transpose WITH barriers (R8: never rely on
// unbarriered LDS ordering). Two [32][33] tiles per round: 8 rounds x 2
// barriers = 16 block-wide barriers (was 32).
__global__ __launch_bounds__(256) void fgt_kernel(const float* __restrict__ x,
                                                  const _Float16* __restrict__ wfgt,
                                                  _Float16* __restrict__ f,
                                                  _Float16* __restrict__ g,
                                                  _Float16* __restrict__ xT) {
  __shared__ float tile[2][32][33];
  int tid  = threadIdx.x;
  int wave = tid >> 6, lane = tid & 63;
  int n16  = lane & 15, quad = lane >> 4;
  int row  = blockIdx.x * 64 + wave * 16 + n16;   // A m-index (global row)
  float4_t acc[8];
#pragma unroll
  for (int t = 0; t < 8; t++) acc[t] = (float4_t){0.f, 0.f, 0.f, 0.f};
  for (int k0 = 0; k0 < 256; k0 += 32) {
    const float* xp = x + (size_t)row * C_ + k0 + quad * 8;
    float4_t x0 = *(const float4_t*)xp;
    float4_t x1 = *(const float4_t*)(xp + 4);
    half8 af;
#pragma unroll
    for (int j = 0; j < 4; j++) { af[j] = (_Float16)x0[j]; af[4 + j] = (_Float16)x1[j]; }
#pragma unroll
    for (int t = 0; t < 8; t++) {
      half8 bf = *(const half8*)(wfgt + (size_t)(t * 16 + n16) * 256 + k0 + quad * 8);
      acc[t] = mfma16(af, bf, acc[t]);
    }
  }
  int orow = blockIdx.x * 64 + wave * 16 + quad * 4;  // D row = quad*4+reg
#pragma unroll
  for (int t = 0; t < 8; t++) {
#pragma unroll
    for (int r = 0; r < 4; r++) {
      _Float16 v = (_Float16)acc[t][r];
      int col = t * 16 + n16;
      if (t < 4) f[(size_t)(orow + r) * 64 + col] = v;
      else       g[(size_t)(orow + r) * 64 + col - 64] = v;
    }
  }

  // ---- Phase B: transpose this block's 64 rows x 256 cols into xT -------------
  const int b   = blockIdx.x >> 6;
  const int nb  = (blockIdx.x & 63) << 6;           // n-tile base (64 rows)
  const int tr  = tid >> 3;                          // 0..31
  const int tc  = (tid & 7) << 2;                    // 0,4,..,28
#pragma unroll 1
  for (int s = 0; s < 8; ++s) {
    const int n0  = nb + ((s & 1) << 5);             // n sub-block (32)
    const int c0p = (s >> 1) << 6;                   // 64-col chunk
    __syncthreads();                                 // protect tile reuse (WAR)
#pragma unroll
    for (int h = 0; h < 2; ++h) {
      const float* src = x + ((size_t)(b * N_ + n0 + tr)) * C_ + c0p + h * 32 + tc;
      float4_t v = *(const float4_t*)src;
      tile[h][tr][tc + 0] = v[0]; tile[h][tr][tc + 1] = v[1];
      tile[h][tr][tc + 2] = v[2]; tile[h][tr][tc + 3] = v[3];
    }
    __syncthreads();
#pragma unroll
    for (int h = 0; h < 2; ++h) {
      half4_t o;
      o[0] = (_Float16)tile[h][tc + 0][tr];
      o[1] = (_Float16)tile[h][tc + 1][tr];
      o[2] = (_Float16)tile[h][tc + 2][tr];
      o[3] = (_Float16)tile[h][tc + 3][tr];
      _Float16* dst = xT + ((size_t)(b * C_ + c0p + h * 32 + tr)) * N_ + n0 + tc;
      *(half4_t*)dst = o;
    }
  }
}

// ---------------- flash attention (C-split): a = softmax(f g^T) @ x --------------
// R1/R6 structure (150 us) with ONE isolated change: K staging via async
// global_load_lds (stage_k) instead of register prefetch + ds_write. Removes
// 2 global loads + 2 ds_write_b128 + address VALU per thread/iter and ~8 VGPR.
// Race-free: stage into buf^1 issues after the barrier that ended the previous
// iter (all reads of buf^1 done); drains at this iter's barrier vmcnt(0).
__global__ __launch_bounds__(256, 2) void flash_kernel(const _Float16* __restrict__ f,
                                                       const _Float16* __restrict__ g,
                                                       const _Float16* __restrict__ xT,
                                                       _Float16* __restrict__ a) {
  __shared__ _Float16 ktb2[2][64 * 64];   // K tile, swizzled
  __shared__ _Float16 ptb2[2][64 * 64];   // P tile, swizzled
  __shared__ float alpha_lds[2][64];
  __shared__ float linv_lds[64];

  const int b   = blockIdx.x;
  const int i0  = blockIdx.y * 64;
  const int tid = threadIdx.x;
  const int wave = tid >> 6, lane = tid & 63;
  const int n16 = lane & 15, quad = lane >> 4;
  const int nlo = n16 & 7, nhi = n16 >> 3;

  // Q fragments (A-layout: m=n16, k=quad*8+j), rows 16w..16w+15 of this i-tile
  half8 qf[2];
  {
    const _Float16* qp = f + (size_t)(b * N_ + i0 + wave * 16 + n16) * 64 + quad * 8;
    qf[0] = *(const half8*)qp;
    qf[1] = *(const half8*)(qp + 32);
  }

  float4_t o_acc[16];   // [ti*4+ct]: rows ti*16+4q+r, cols 64w+16ct+n16
#pragma unroll
  for (int t = 0; t < 16; t++) o_acc[t] = (float4_t){0.f, 0.f, 0.f, 0.f};
  float m_i[4] = {-1e30f, -1e30f, -1e30f, -1e30f};   // log2-domain running max
  float l_i[4] = {0.f, 0.f, 0.f, 0.f};

  const _Float16* gbase = g + (size_t)(b * N_) * 64;
  const _Float16* xbase = xT + ((size_t)b * C_ + 64 * wave) * (size_t)N_;

  // stage K tile for j0=0 (async; drained by the barrier)
  stage_k(gbase, ktb2[0], wave, lane);
  __syncthreads();

  for (int k = 0; k < 64; ++k) {
    const int j0  = k << 6;
    const int buf = k & 1;
    const int j0n = (j0 + 64) & (N_ - 1);

    // async-stage next K tile into the other buffer (lands by this iter's barrier)
    stage_k(gbase + (size_t)j0n * 64, ktb2[buf ^ 1], wave, lane);

    // V fragments for this iter straight from global (L2)
    half8 vfr[8];
#pragma unroll
    for (int s = 0; s < 2; s++)
#pragma unroll
      for (int ct = 0; ct < 4; ct++)
        vfr[s * 4 + ct] = *(const half8*)(xbase + (size_t)(16 * ct + n16) * N_ +
                                          j0 + 32 * s + 8 * quad);

    // S = Q K^T for this wave's 16 rows (log2-scaled via prep)
    float4_t s_acc[4];
#pragma unroll
    for (int t = 0; t < 4; t++) s_acc[t] = (float4_t){0.f, 0.f, 0.f, 0.f};
    {
      const _Float16* ktb = ktb2[buf];
      __builtin_amdgcn_s_setprio(1);
#pragma unroll
      for (int s = 0; s < 2; s++)
#pragma unroll
        for (int t = 0; t < 4; t++) {
          half8 bf = *(const half8*)(ktb + (16 * t + n16) * 64 +
                                     (((4 * s + quad) ^ nlo) << 3));
          s_acc[t] = mfma16(qf[s], bf, s_acc[t]);
        }
      __builtin_amdgcn_s_setprio(0);
    }

    // online softmax (base-2) for this wave's rows; write P (swizzled) + alpha
    float alpha_r[4];
#pragma unroll
    for (int r = 0; r < 4; r++) {
      float v = fmaxf(fmaxf(s_acc[0][r], s_acc[1][r]),
                      fmaxf(s_acc[2][r], s_acc[3][r]));
      v = row_max16(v);                      // DPP reduce, no LDS traffic
      float mn = fmaxf(m_i[r], v);
      alpha_r[r] = EXP2(m_i[r] - mn);
      m_i[r] = mn;
    }
    _Float16* pb = ptb2[buf];
#pragma unroll
    for (int r = 0; r < 4; r++) {
      float s0 = EXP2(s_acc[0][r] - m_i[r]);
      float s1 = EXP2(s_acc[1][r] - m_i[r]);
      float s2 = EXP2(s_acc[2][r] - m_i[r]);
      float s3 = EXP2(s_acc[3][r] - m_i[r]);
      float v = row_sum16(s0 + s1 + s2 + s3); // DPP reduce
      l_i[r] = l_i[r] * alpha_r[r] + v;
      const int row = wave * 16 + 4 * quad + r;
      const int rb  = row & 7;
      _Float16* pr = pb + row * 64 + nlo;
      pr[((nhi    ) ^ rb) << 3] = (_Float16)s0;
      pr[((nhi + 2) ^ rb) << 3] = (_Float16)s1;
      pr[((nhi + 4) ^ rb) << 3] = (_Float16)s2;
      pr[((nhi + 6) ^ rb) << 3] = (_Float16)s3;
    }
    if (n16 == 0) {
#pragma unroll
      for (int r = 0; r < 4; r++)
        alpha_lds[buf][wave * 16 + 4 * quad + r] = alpha_r[r];
    }
    __syncthreads();

    // rescale O by alpha of each row (broadcast LDS reads)
#pragma unroll
    for (int ti = 0; ti < 4; ti++)
#pragma unroll
      for (int r = 0; r < 4; r++) {
        float al = alpha_lds[buf][ti * 16 + 4 * quad + r];
#pragma unroll
        for (int ct = 0; ct < 4; ct++) o_acc[ti * 4 + ct][r] *= al;
      }

    // O += P V  (P from shared LDS, V from regs)
    __builtin_amdgcn_s_setprio(1);
#pragma unroll
    for (int s = 0; s < 2; s++)
#pragma unroll
      for (int ti = 0; ti < 4; ti++) {
        half8 af = *(const half8*)(pb + (16 * ti + n16) * 64 +
                                   (((4 * s + quad) ^ nlo) << 3));
#pragma unroll
        for (int ct = 0; ct < 4; ct++)
          o_acc[ti * 4 + ct] = mfma16(af, vfr[s * 4 + ct], o_acc[ti * 4 + ct]);
      }
    __builtin_amdgcn_s_setprio(0);
  }

  // share 1/l across waves, then write out a = O / l
  if (n16 == 0) {
#pragma unroll
    for (int r = 0; r < 4; r++)
      linv_lds[wave * 16 + 4 * quad + r] = 1.f / l_i[r];
  }
  __syncthreads();
#pragma unroll
  for (int ti = 0; ti < 4; ti++)
#pragma unroll
    for (int r = 0; r < 4; r++) {
      float il = linv_lds[ti * 16 + 4 * quad + r];
      size_t orow = (size_t)(b * N_ + i0 + ti * 16 + 4 * quad + r) * C_;
#pragma unroll
      for (int ct = 0; ct < 4; ct++)
        a[orow + 64 * wave + 16 * ct + n16] =
            (_Float16)(o_acc[ti * 4 + ct][r] * il);
    }
}

// ---------------- epilogue GEMM: out = gamma * (a @ Whv) + x ---------------------
// Column-split grid (512, 4): measured neutral vs unsplit (R9); kept for the
// occupancy headroom (2048 blocks, 16 f32 acc/lane).
__global__ __launch_bounds__(256) void out_kernel(const _Float16* __restrict__ a,
                                                  const _Float16* __restrict__ whvt,
                                                  const float* __restrict__ x,
                                                  const float* __restrict__ gamma,
                                                  float* __restrict__ out) {
  int tid  = threadIdx.x;
  int wave = tid >> 6, lane = tid & 63;
  int n16  = lane & 15, quad = lane >> 4;
  int row  = blockIdx.x * 64 + wave * 16 + n16;   // A m-index
  int col0 = blockIdx.y * 64;                      // this block's 64-col slice
  float4_t acc[4];
#pragma unroll
  for (int t = 0; t < 4; t++) acc[t] = (float4_t){0.f, 0.f, 0.f, 0.f};
  for (int k0 = 0; k0 < 256; k0 += 32) {
    half8 af = *(const half8*)(a + (size_t)row * C_ + k0 + quad * 8);
#pragma unroll
    for (int t = 0; t < 4; t++) {
      half8 bf = *(const half8*)(whvt +
                  (size_t)(col0 + t * 16 + n16) * 256 + k0 + quad * 8);
      acc[t] = mfma16(af, bf, acc[t]);
    }
  }
  float gm = gamma[0];
  int orow = blockIdx.x * 64 + wave * 16 + quad * 4;
#pragma unroll
  for (int t = 0; t < 4; t++) {
#pragma unroll
    for (int r = 0; r < 4; r++) {
      size_t idx = (size_t)(orow + r) * C_ + col0 + t * 16 + n16;
      out[idx] = gm * acc[t][r] + x[idx];
    }
  }
}

extern "C" void kernel_launch(void* const* d_in, const int* in_sizes, int n_in,
                              void* d_out, int out_size, void* d_ws, size_t ws_size,
                              hipStream_t stream) {
  const float* x     = (const float*)d_in[0];
  const float* Wf    = (const float*)d_in[1];
  const float* Wg    = (const float*)d_in[2];
  const float* Wh    = (const float*)d_in[3];
  const float* Wv    = (const float*)d_in[4];
  const float* gamma = (const float*)d_in[5];
  float* out = (float*)d_out;

  char* w = (char*)d_ws;
  _Float16* whvt = (_Float16*)(w);                                  // 128 KiB
  _Float16* wfgt = (_Float16*)(w + 131072);                         //  64 KiB
  _Float16* fb   = (_Float16*)(w + 196608);                         //   4 MiB
  _Float16* gb   = (_Float16*)(w + 196608 + 4194304);               //   4 MiB
  _Float16* xT   = (_Float16*)(w + 196608 + 2 * 4194304);           //  16 MiB
  _Float16* ab   = (_Float16*)(w + 196608 + 2 * 4194304 + 16777216);//  16 MiB

  hipLaunchKernelGGL(prep_kernel, dim3(384),   dim3(256), 0, stream,
                     Wh, Wv, Wf, Wg, whvt, wfgt);
  hipLaunchKernelGGL(fgt_kernel,  dim3(512),   dim3(256), 0, stream,
                     x, wfgt, fb, gb, xT);
  hipLaunchKernelGGL(flash_kernel, dim3(8, 64), dim3(256), 0, stream, fb, gb, xT, ab);
  hipLaunchKernelGGL(out_kernel,  dim3(512, 4), dim3(256), 0, stream,
                     ab, whvt, x, gamma, out);
}

// Round 11
// 285.899 us; speedup vs baseline: 1.0941x; 1.0941x over previous
//
#include <hip/hip_runtime.h>

typedef _Float16 half8   __attribute__((ext_vector_type(8)));
typedef _Float16 half4_t __attribute__((ext_vector_type(4)));
typedef float    float4_t __attribute__((ext_vector_type(4)));

#define B_   8
#define N_   4096
#define C_   256
#define F_   64

#if defined(__has_builtin) && __has_builtin(__builtin_amdgcn_exp2f)
#define EXP2(x) __builtin_amdgcn_exp2f(x)
#else
#define EXP2(x) exp2f(x)
#endif
#define LOG2E 1.44269504f

static __device__ __forceinline__ float4_t mfma16(half8 a, half8 b, float4_t c) {
  return __builtin_amdgcn_mfma_f32_16x16x32_f16(a, b, c, 0, 0, 0);
}

// DPP cross-lane within 16-lane rows: row_ror:N = 0x120|N.
template <int CTRL>
static __device__ __forceinline__ float dpp_f(float x) {
  return __int_as_float(__builtin_amdgcn_update_dpp(
      __float_as_int(x), __float_as_int(x), CTRL, 0xF, 0xF, false));
}
static __device__ __forceinline__ float row_max16(float v) {
  v = fmaxf(v, dpp_f<0x128>(v));
  v = fmaxf(v, dpp_f<0x124>(v));
  v = fmaxf(v, dpp_f<0x122>(v));
  v = fmaxf(v, dpp_f<0x121>(v));
  return v;
}
static __device__ __forceinline__ float row_sum16(float v) {
  v += dpp_f<0x128>(v);
  v += dpp_f<0x124>(v);
  v += dpp_f<0x122>(v);
  v += dpp_f<0x121>(v);
  return v;
}

// ------------- fused prep: whvt (blocks 0..255) + wfgt (blocks 256..383) ---------
__global__ __launch_bounds__(256) void prep_kernel(const float* __restrict__ Wh,
                                                   const float* __restrict__ Wv,
                                                   const float* __restrict__ Wf,
                                                   const float* __restrict__ Wg,
                                                   _Float16* __restrict__ whvt,
                                                   _Float16* __restrict__ wfgt) {
  int c = threadIdx.x;
  if (blockIdx.x < 256) {
    int d = blockIdx.x;    // uniform per block -> Wv reads become s_loads
    const float4_t* whr = (const float4_t*)(Wh + (size_t)c * 256);
    float acc = 0.f;
#pragma unroll 8
    for (int e4 = 0; e4 < 64; ++e4) {
      float4_t w4 = whr[e4];
      acc += w4[0] * Wv[(e4 * 4 + 0) * 256 + d];
      acc += w4[1] * Wv[(e4 * 4 + 1) * 256 + d];
      acc += w4[2] * Wv[(e4 * 4 + 2) * 256 + d];
      acc += w4[3] * Wv[(e4 * 4 + 3) * 256 + d];
    }
    whvt[d * 256 + c] = (_Float16)acc;
  } else {
    int n = blockIdx.x - 256;   // 0..127
    float v = (n < 64) ? Wf[c * 64 + n] * LOG2E : Wg[c * 64 + (n - 64)];
    wfgt[n * 256 + c] = (_Float16)v;
  }
}

// ------- fused f,g GEMM + x transpose, ROW-SPLIT to 32 rows/block ----------------
// fgt was grid-capped at 2 blocks/CU (512 blocks). Row-split doubles the grid to
// 1024 with ZERO extra HBM traffic (each x row still read once): waves {0,1} own
// rows {0-15,16-31} of the tile; wave>>1 picks the f/g column half (4 col-tiles,
// acc[4]). Phase B transposes this block's 32 rows x 256 cols, same proven
// barriered shared-tile pattern (R8 lesson: never skip __syncthreads on LDS).
__global__ __launch_bounds__(256) void fgt_kernel(const float* __restrict__ x,
                                                  const _Float16* __restrict__ wfgt,
                                                  _Float16* __restrict__ f,
                                                  _Float16* __restrict__ g,
                                                  _Float16* __restrict__ xT) {
  __shared__ float tile[2][32][33];
  int tid  = threadIdx.x;
  int wave = tid >> 6, lane = tid & 63;
  int n16  = lane & 15, quad = lane >> 4;
  const int wrow = wave & 1;          // which 16-row half of the 32-row tile
  const int wcol = wave >> 1;         // 0 -> f, 1 -> g
  int row  = blockIdx.x * 32 + wrow * 16 + n16;   // A m-index (global row)
  float4_t acc[4];
#pragma unroll
  for (int t = 0; t < 4; t++) acc[t] = (float4_t){0.f, 0.f, 0.f, 0.f};
  for (int k0 = 0; k0 < 256; k0 += 32) {
    const float* xp = x + (size_t)row * C_ + k0 + quad * 8;
    float4_t x0 = *(const float4_t*)xp;
    float4_t x1 = *(const float4_t*)(xp + 4);
    half8 af;
#pragma unroll
    for (int j = 0; j < 4; j++) { af[j] = (_Float16)x0[j]; af[4 + j] = (_Float16)x1[j]; }
#pragma unroll
    for (int t = 0; t < 4; t++) {
      half8 bf = *(const half8*)(wfgt +
                  (size_t)(wcol * 64 + t * 16 + n16) * 256 + k0 + quad * 8);
      acc[t] = mfma16(af, bf, acc[t]);
    }
  }
  int orow = blockIdx.x * 32 + wrow * 16 + quad * 4;  // D row = quad*4+reg
  _Float16* dstfg = wcol ? g : f;
#pragma unroll
  for (int t = 0; t < 4; t++) {
#pragma unroll
    for (int r = 0; r < 4; r++) {
      dstfg[(size_t)(orow + r) * 64 + t * 16 + n16] = (_Float16)acc[t][r];
    }
  }

  // ---- Phase B: transpose this block's 32 rows x 256 cols into xT -------------
  const int b   = blockIdx.x >> 7;                   // 128 blocks per batch
  const int nb  = (blockIdx.x & 127) << 5;           // n-tile base (32 rows)
  const int tr  = tid >> 3;                          // 0..31
  const int tc  = (tid & 7) << 2;                    // 0,4,..,28
#pragma unroll 1
  for (int s = 0; s < 4; ++s) {
    const int c0p = s << 6;                          // 64-col chunk
    __syncthreads();                                 // protect tile reuse (WAR)
#pragma unroll
    for (int h = 0; h < 2; ++h) {
      const float* src = x + ((size_t)(b * N_ + nb + tr)) * C_ + c0p + h * 32 + tc;
      float4_t v = *(const float4_t*)src;
      tile[h][tr][tc + 0] = v[0]; tile[h][tr][tc + 1] = v[1];
      tile[h][tr][tc + 2] = v[2]; tile[h][tr][tc + 3] = v[3];
    }
    __syncthreads();
#pragma unroll
    for (int h = 0; h < 2; ++h) {
      half4_t o;
      o[0] = (_Float16)tile[h][tc + 0][tr];
      o[1] = (_Float16)tile[h][tc + 1][tr];
      o[2] = (_Float16)tile[h][tc + 2][tr];
      o[3] = (_Float16)tile[h][tc + 3][tr];
      _Float16* dst = xT + ((size_t)(b * C_ + c0p + h * 32 + tr)) * N_ + nb + tc;
      *(half4_t*)dst = o;
    }
  }
}

// ---------------- flash attention (C-split): a = softmax(f g^T) @ x --------------
// R9-exact (151.6 us measured). Structure: KVBLK=64, REGISTER K-prefetch +
// ds_write (R10 measured global_load_lds staging at -17% -- do not reinstate),
// all V loads at iter top, (256,2) -> ~160 unified regs, 2 blocks/CU, no spill.
__global__ __launch_bounds__(256, 2) void flash_kernel(const _Float16* __restrict__ f,
                                                       const _Float16* __restrict__ g,
                                                       const _Float16* __restrict__ xT,
                                                       _Float16* __restrict__ a) {
  __shared__ _Float16 ktb2[2][64 * 64];   // K tile, swizzled
  __shared__ _Float16 ptb2[2][64 * 64];   // P tile, swizzled
  __shared__ float alpha_lds[2][64];
  __shared__ float linv_lds[64];

  const int b   = blockIdx.x;
  const int i0  = blockIdx.y * 64;
  const int tid = threadIdx.x;
  const int wave = tid >> 6, lane = tid & 63;
  const int n16 = lane & 15, quad = lane >> 4;
  const int nlo = n16 & 7, nhi = n16 >> 3;

  // Q fragments (A-layout: m=n16, k=quad*8+j), rows 16w..16w+15 of this i-tile
  half8 qf[2];
  {
    const _Float16* qp = f + (size_t)(b * N_ + i0 + wave * 16 + n16) * 64 + quad * 8;
    qf[0] = *(const half8*)qp;
    qf[1] = *(const half8*)(qp + 32);
  }

  float4_t o_acc[16];   // [ti*4+ct]: rows ti*16+4q+r, cols 64w+16ct+n16
#pragma unroll
  for (int t = 0; t < 16; t++) o_acc[t] = (float4_t){0.f, 0.f, 0.f, 0.f};
  float m_i[4] = {-1e30f, -1e30f, -1e30f, -1e30f};   // log2-domain running max
  float l_i[4] = {0.f, 0.f, 0.f, 0.f};

  const _Float16* gbase = g + (size_t)(b * N_) * 64;
  const _Float16* xbase = xT + ((size_t)b * C_ + 64 * wave) * (size_t)N_;

  // K staging geometry: thread covers row krow, col blocks kcb, kcb+1
  const int krow = tid >> 2;
  const int kcb  = (tid & 3) << 1;
  const int krb  = krow & 7;

  // stage K tile for j0=0
  {
    const _Float16* ks = gbase + (size_t)krow * 64 + (kcb << 3);
    half8 k0 = *(const half8*)ks;
    half8 k1 = *(const half8*)(ks + 8);
    _Float16* kd = ktb2[0] + krow * 64;
    *(half8*)(kd + (((kcb    ) ^ krb) << 3)) = k0;
    *(half8*)(kd + (((kcb + 1) ^ krb) << 3)) = k1;
  }
  __syncthreads();

  for (int k = 0; k < 64; ++k) {
    const int j0  = k << 6;
    const int buf = k & 1;
    const int j0n = (j0 + 64) & (N_ - 1);

    // prefetch next K tile into regs
    half8 kp0, kp1;
    {
      const _Float16* ks = gbase + (size_t)(j0n + krow) * 64 + (kcb << 3);
      kp0 = *(const half8*)ks;
      kp1 = *(const half8*)(ks + 8);
    }
    // V fragments for this iter straight from global (L2)
    half8 vfr[8];
#pragma unroll
    for (int s = 0; s < 2; s++)
#pragma unroll
      for (int ct = 0; ct < 4; ct++)
        vfr[s * 4 + ct] = *(const half8*)(xbase + (size_t)(16 * ct + n16) * N_ +
                                          j0 + 32 * s + 8 * quad);

    // S = Q K^T for this wave's 16 rows (log2-scaled via prep)
    float4_t s_acc[4];
#pragma unroll
    for (int t = 0; t < 4; t++) s_acc[t] = (float4_t){0.f, 0.f, 0.f, 0.f};
    {
      const _Float16* ktb = ktb2[buf];
      __builtin_amdgcn_s_setprio(1);
#pragma unroll
      for (int s = 0; s < 2; s++)
#pragma unroll
        for (int t = 0; t < 4; t++) {
          half8 bf = *(const half8*)(ktb + (16 * t + n16) * 64 +
                                     (((4 * s + quad) ^ nlo) << 3));
          s_acc[t] = mfma16(qf[s], bf, s_acc[t]);
        }
      __builtin_amdgcn_s_setprio(0);
    }

    // online softmax (base-2) for this wave's rows; write P (swizzled) + alpha
    float alpha_r[4];
#pragma unroll
    for (int r = 0; r < 4; r++) {
      float v = fmaxf(fmaxf(s_acc[0][r], s_acc[1][r]),
                      fmaxf(s_acc[2][r], s_acc[3][r]));
      v = row_max16(v);                      // DPP reduce, no LDS traffic
      float mn = fmaxf(m_i[r], v);
      alpha_r[r] = EXP2(m_i[r] - mn);
      m_i[r] = mn;
    }
    _Float16* pb = ptb2[buf];
#pragma unroll
    for (int r = 0; r < 4; r++) {
      float s0 = EXP2(s_acc[0][r] - m_i[r]);
      float s1 = EXP2(s_acc[1][r] - m_i[r]);
      float s2 = EXP2(s_acc[2][r] - m_i[r]);
      float s3 = EXP2(s_acc[3][r] - m_i[r]);
      float v = row_sum16(s0 + s1 + s2 + s3); // DPP reduce
      l_i[r] = l_i[r] * alpha_r[r] + v;
      const int row = wave * 16 + 4 * quad + r;
      const int rb  = row & 7;
      _Float16* pr = pb + row * 64 + nlo;
      pr[((nhi    ) ^ rb) << 3] = (_Float16)s0;
      pr[((nhi + 2) ^ rb) << 3] = (_Float16)s1;
      pr[((nhi + 4) ^ rb) << 3] = (_Float16)s2;
      pr[((nhi + 6) ^ rb) << 3] = (_Float16)s3;
    }
    if (n16 == 0) {
#pragma unroll
      for (int r = 0; r < 4; r++)
        alpha_lds[buf][wave * 16 + 4 * quad + r] = alpha_r[r];
    }
    // write prefetched K tile into other buffer
    {
      _Float16* kd = ktb2[buf ^ 1] + krow * 64;
      *(half8*)(kd + (((kcb    ) ^ krb) << 3)) = kp0;
      *(half8*)(kd + (((kcb + 1) ^ krb) << 3)) = kp1;
    }
    __syncthreads();

    // rescale O by alpha of each row (broadcast LDS reads)
#pragma unroll
    for (int ti = 0; ti < 4; ti++)
#pragma unroll
      for (int r = 0; r < 4; r++) {
        float al = alpha_lds[buf][ti * 16 + 4 * quad + r];
#pragma unroll
        for (int ct = 0; ct < 4; ct++) o_acc[ti * 4 + ct][r] *= al;
      }

    // O += P V  (P from shared LDS, V from regs)
    __builtin_amdgcn_s_setprio(1);
#pragma unroll
    for (int s = 0; s < 2; s++)
#pragma unroll
      for (int ti = 0; ti < 4; ti++) {
        half8 af = *(const half8*)(pb + (16 * ti + n16) * 64 +
                                   (((4 * s + quad) ^ nlo) << 3));
#pragma unroll
        for (int ct = 0; ct < 4; ct++)
          o_acc[ti * 4 + ct] = mfma16(af, vfr[s * 4 + ct], o_acc[ti * 4 + ct]);
      }
    __builtin_amdgcn_s_setprio(0);
  }

  // share 1/l across waves, then write out a = O / l
  if (n16 == 0) {
#pragma unroll
    for (int r = 0; r < 4; r++)
      linv_lds[wave * 16 + 4 * quad + r] = 1.f / l_i[r];
  }
  __syncthreads();
#pragma unroll
  for (int ti = 0; ti < 4; ti++)
#pragma unroll
    for (int r = 0; r < 4; r++) {
      float il = linv_lds[ti * 16 + 4 * quad + r];
      size_t orow = (size_t)(b * N_ + i0 + ti * 16 + 4 * quad + r) * C_;
#pragma unroll
      for (int ct = 0; ct < 4; ct++)
        a[orow + 64 * wave + 16 * ct + n16] =
            (_Float16)(o_acc[ti * 4 + ct][r] * il);
    }
}

// ---------------- epilogue GEMM: out = gamma * (a @ Whv) + x ---------------------
// Column-split grid (512, 4): measured neutral vs unsplit (R9); kept for the
// occupancy headroom (2048 blocks, 16 f32 acc/lane).
__global__ __launch_bounds__(256) void out_kernel(const _Float16* __restrict__ a,
                                                  const _Float16* __restrict__ whvt,
                                                  const float* __restrict__ x,
                                                  const float* __restrict__ gamma,
                                                  float* __restrict__ out) {
  int tid  = threadIdx.x;
  int wave = tid >> 6, lane = tid & 63;
  int n16  = lane & 15, quad = lane >> 4;
  int row  = blockIdx.x * 64 + wave * 16 + n16;   // A m-index
  int col0 = blockIdx.y * 64;                      // this block's 64-col slice
  float4_t acc[4];
#pragma unroll
  for (int t = 0; t < 4; t++) acc[t] = (float4_t){0.f, 0.f, 0.f, 0.f};
  for (int k0 = 0; k0 < 256; k0 += 32) {
    half8 af = *(const half8*)(a + (size_t)row * C_ + k0 + quad * 8);
#pragma unroll
    for (int t = 0; t < 4; t++) {
      half8 bf = *(const half8*)(whvt +
                  (size_t)(col0 + t * 16 + n16) * 256 + k0 + quad * 8);
      acc[t] = mfma16(af, bf, acc[t]);
    }
  }
  float gm = gamma[0];
  int orow = blockIdx.x * 64 + wave * 16 + quad * 4;
#pragma unroll
  for (int t = 0; t < 4; t++) {
#pragma unroll
    for (int r = 0; r < 4; r++) {
      size_t idx = (size_t)(orow + r) * C_ + col0 + t * 16 + n16;
      out[idx] = gm * acc[t][r] + x[idx];
    }
  }
}

extern "C" void kernel_launch(void* const* d_in, const int* in_sizes, int n_in,
                              void* d_out, int out_size, void* d_ws, size_t ws_size,
                              hipStream_t stream) {
  const float* x     = (const float*)d_in[0];
  const float* Wf    = (const float*)d_in[1];
  const float* Wg    = (const float*)d_in[2];
  const float* Wh    = (const float*)d_in[3];
  const float* Wv    = (const float*)d_in[4];
  const float* gamma = (const float*)d_in[5];
  float* out = (float*)d_out;

  char* w = (char*)d_ws;
  _Float16* whvt = (_Float16*)(w);                                  // 128 KiB
  _Float16* wfgt = (_Float16*)(w + 131072);                         //  64 KiB
  _Float16* fb   = (_Float16*)(w + 196608);                         //   4 MiB
  _Float16* gb   = (_Float16*)(w + 196608 + 4194304);               //   4 MiB
  _Float16* xT   = (_Float16*)(w + 196608 + 2 * 4194304);           //  16 MiB
  _Float16* ab   = (_Float16*)(w + 196608 + 2 * 4194304 + 16777216);//  16 MiB

  hipLaunchKernelGGL(prep_kernel, dim3(384),    dim3(256), 0, stream,
                     Wh, Wv, Wf, Wg, whvt, wfgt);
  hipLaunchKernelGGL(fgt_kernel,  dim3(1024),   dim3(256), 0, stream,
                     x, wfgt, fb, gb, xT);
  hipLaunchKernelGGL(flash_kernel, dim3(8, 64), dim3(256), 0, stream, fb, gb, xT, ab);
  hipLaunchKernelGGL(out_kernel,  dim3(512, 4), dim3(256), 0, stream,
                     ab, whvt, x, gamma, out);
}

// Round 12
// 259.530 us; speedup vs baseline: 1.2053x; 1.1016x over previous
//
#include <hip/hip_runtime.h>

typedef _Float16 half8   __attribute__((ext_vector_type(8)));
typedef _Float16 half4_t __attribute__((ext_vector_type(4)));
typedef float    float4_t __attribute__((ext_vector_type(4)));

#define B_   8
#define N_   4096
#define C_   256
#define F_   64

#if defined(__has_builtin) && __has_builtin(__builtin_amdgcn_exp2f)
#define EXP2(x) __builtin_amdgcn_exp2f(x)
#else
#define EXP2(x) exp2f(x)
#endif
#define LOG2E 1.44269504f

static __device__ __forceinline__ float4_t mfma16(half8 a, half8 b, float4_t c) {
  return __builtin_amdgcn_mfma_f32_16x16x32_f16(a, b, c, 0, 0, 0);
}

// DPP cross-lane within 16-lane rows: row_ror:N = 0x120|N.
template <int CTRL>
static __device__ __forceinline__ float dpp_f(float x) {
  return __int_as_float(__builtin_amdgcn_update_dpp(
      __float_as_int(x), __float_as_int(x), CTRL, 0xF, 0xF, false));
}
static __device__ __forceinline__ float row_max16(float v) {
  v = fmaxf(v, dpp_f<0x128>(v));
  v = fmaxf(v, dpp_f<0x124>(v));
  v = fmaxf(v, dpp_f<0x122>(v));
  v = fmaxf(v, dpp_f<0x121>(v));
  return v;
}
static __device__ __forceinline__ float row_sum16(float v) {
  v += dpp_f<0x128>(v);
  v += dpp_f<0x124>(v);
  v += dpp_f<0x122>(v);
  v += dpp_f<0x121>(v);
  return v;
}

// ------------- fused prep: whvt (blocks 0..255) + wfgt (blocks 256..383) ---------
__global__ __launch_bounds__(256) void prep_kernel(const float* __restrict__ Wh,
                                                   const float* __restrict__ Wv,
                                                   const float* __restrict__ Wf,
                                                   const float* __restrict__ Wg,
                                                   _Float16* __restrict__ whvt,
                                                   _Float16* __restrict__ wfgt) {
  int c = threadIdx.x;
  if (blockIdx.x < 256) {
    int d = blockIdx.x;    // uniform per block -> Wv reads become s_loads
    const float4_t* whr = (const float4_t*)(Wh + (size_t)c * 256);
    float acc = 0.f;
#pragma unroll 8
    for (int e4 = 0; e4 < 64; ++e4) {
      float4_t w4 = whr[e4];
      acc += w4[0] * Wv[(e4 * 4 + 0) * 256 + d];
      acc += w4[1] * Wv[(e4 * 4 + 1) * 256 + d];
      acc += w4[2] * Wv[(e4 * 4 + 2) * 256 + d];
      acc += w4[3] * Wv[(e4 * 4 + 3) * 256 + d];
    }
    whvt[d * 256 + c] = (_Float16)acc;
  } else {
    int n = blockIdx.x - 256;   // 0..127
    float v = (n < 64) ? Wf[c * 64 + n] * LOG2E : Wg[c * 64 + (n - 64)];
    wfgt[n * 256 + c] = (_Float16)v;
  }
}

// ------- fused f,g GEMM + x transpose, ROW-SPLIT to 32 rows/block ----------------
// (R11 green version, unchanged.)
__global__ __launch_bounds__(256) void fgt_kernel(const float* __restrict__ x,
                                                  const _Float16* __restrict__ wfgt,
                                                  _Float16* __restrict__ f,
                                                  _Float16* __restrict__ g,
                                                  _Float16* __restrict__ xT) {
  __shared__ float tile[2][32][33];
  int tid  = threadIdx.x;
  int wave = tid >> 6, lane = tid & 63;
  int n16  = lane & 15, quad = lane >> 4;
  const int wrow = wave & 1;          // which 16-row half of the 32-row tile
  const int wcol = wave >> 1;         // 0 -> f, 1 -> g
  int row  = blockIdx.x * 32 + wrow * 16 + n16;   // A m-index (global row)
  float4_t acc[4];
#pragma unroll
  for (int t = 0; t < 4; t++) acc[t] = (float4_t){0.f, 0.f, 0.f, 0.f};
  for (int k0 = 0; k0 < 256; k0 += 32) {
    const float* xp = x + (size_t)row * C_ + k0 + quad * 8;
    float4_t x0 = *(const float4_t*)xp;
    float4_t x1 = *(const float4_t*)(xp + 4);
    half8 af;
#pragma unroll
    for (int j = 0; j < 4; j++) { af[j] = (_Float16)x0[j]; af[4 + j] = (_Float16)x1[j]; }
#pragma unroll
    for (int t = 0; t < 4; t++) {
      half8 bf = *(const half8*)(wfgt +
                  (size_t)(wcol * 64 + t * 16 + n16) * 256 + k0 + quad * 8);
      acc[t] = mfma16(af, bf, acc[t]);
    }
  }
  int orow = blockIdx.x * 32 + wrow * 16 + quad * 4;  // D row = quad*4+reg
  _Float16* dstfg = wcol ? g : f;
#pragma unroll
  for (int t = 0; t < 4; t++) {
#pragma unroll
    for (int r = 0; r < 4; r++) {
      dstfg[(size_t)(orow + r) * 64 + t * 16 + n16] = (_Float16)acc[t][r];
    }
  }

  // ---- Phase B: transpose this block's 32 rows x 256 cols into xT -------------
  const int b   = blockIdx.x >> 7;                   // 128 blocks per batch
  const int nb  = (blockIdx.x & 127) << 5;           // n-tile base (32 rows)
  const int tr  = tid >> 3;                          // 0..31
  const int tc  = (tid & 7) << 2;                    // 0,4,..,28
#pragma unroll 1
  for (int s = 0; s < 4; ++s) {
    const int c0p = s << 6;                          // 64-col chunk
    __syncthreads();                                 // protect tile reuse (WAR)
#pragma unroll
    for (int h = 0; h < 2; ++h) {
      const float* src = x + ((size_t)(b * N_ + nb + tr)) * C_ + c0p + h * 32 + tc;
      float4_t v = *(const float4_t*)src;
      tile[h][tr][tc + 0] = v[0]; tile[h][tr][tc + 1] = v[1];
      tile[h][tr][tc + 2] = v[2]; tile[h][tr][tc + 3] = v[3];
    }
    __syncthreads();
#pragma unroll
    for (int h = 0; h < 2; ++h) {
      half4_t o;
      o[0] = (_Float16)tile[h][tc + 0][tr];
      o[1] = (_Float16)tile[h][tc + 1][tr];
      o[2] = (_Float16)tile[h][tc + 2][tr];
      o[3] = (_Float16)tile[h][tc + 3][tr];
      _Float16* dst = xT + ((size_t)(b * C_ + c0p + h * 32 + tr)) * N_ + nb + tc;
      *(half4_t*)dst = o;
    }
  }
}

// -------- flash attention + fused epilogue: out = gamma*(softmax(fg^T)@x @Whv)+x -
// Main loop: R9-exact 150.6us structure (KVBLK=64, register K-prefetch +
// ds_write, all V loads at iter top, (256,2)). Epilogue (R7 logic, replay-safe
// rebuild): ONE __shared__ f16 array holds K tiles [0,8192), P tiles
// [8192,16384), and after the main loop the 64x256 normalized a-tile [0,16384)
// — single-object indexing means LLVM alias analysis CANNOT reorder these LDS
// accesses across the barriers (R7 used separate pointer-cast views; its
// replay-divergence is attributed to exactly that). sched_barrier(0) after
// each epilogue barrier pins the schedule as a second fence.
__global__ __launch_bounds__(256, 2) void flash_kernel(const _Float16* __restrict__ f,
                                                       const _Float16* __restrict__ g,
                                                       const _Float16* __restrict__ xT,
                                                       const _Float16* __restrict__ whvt,
                                                       const float* __restrict__ x,
                                                       const float* __restrict__ gamma,
                                                       float* __restrict__ out) {
  __shared__ _Float16 smem[16896];        // K: [0,8192) P: [8192,16896-512)... layout below
  __shared__ float alpha_lds[2][64];
  __shared__ float linv_lds[64];
  // layout: ktb(buf) = smem + buf*4096          (2 x 4096 elems = 16 KiB)
  //         ptb(buf) = smem + 8192 + buf*4096   (2 x 4096 elems = 16 KiB)
  //         atile    = smem + 0 .. 16384        (64 rows x 256 cols f16, 32 KiB)

  const int b   = blockIdx.x;
  const int i0  = blockIdx.y * 64;
  const int tid = threadIdx.x;
  const int wave = tid >> 6, lane = tid & 63;
  const int n16 = lane & 15, quad = lane >> 4;
  const int nlo = n16 & 7, nhi = n16 >> 3;

  // Q fragments (A-layout: m=n16, k=quad*8+j); Q pre-scaled by log2e via prep
  half8 qf[2];
  {
    const _Float16* qp = f + (size_t)(b * N_ + i0 + wave * 16 + n16) * 64 + quad * 8;
    qf[0] = *(const half8*)qp;
    qf[1] = *(const half8*)(qp + 32);
  }

  float4_t o_acc[16];   // [ti*4+ct]: rows ti*16+4q+r, cols 64w+16ct+n16
#pragma unroll
  for (int t = 0; t < 16; t++) o_acc[t] = (float4_t){0.f, 0.f, 0.f, 0.f};
  float m_i[4] = {-1e30f, -1e30f, -1e30f, -1e30f};   // log2-domain running max
  float l_i[4] = {0.f, 0.f, 0.f, 0.f};

  const _Float16* gbase = g + (size_t)(b * N_) * 64;
  const _Float16* xbase = xT + ((size_t)b * C_ + 64 * wave) * (size_t)N_;

  // K staging geometry: thread covers row krow, col blocks kcb, kcb+1
  const int krow = tid >> 2;
  const int kcb  = (tid & 3) << 1;
  const int krb  = krow & 7;

  // stage K tile for j0=0
  {
    const _Float16* ks = gbase + (size_t)krow * 64 + (kcb << 3);
    half8 k0 = *(const half8*)ks;
    half8 k1 = *(const half8*)(ks + 8);
    _Float16* kd = smem + krow * 64;
    *(half8*)(kd + (((kcb    ) ^ krb) << 3)) = k0;
    *(half8*)(kd + (((kcb + 1) ^ krb) << 3)) = k1;
  }
  __syncthreads();

  for (int k = 0; k < 64; ++k) {
    const int j0  = k << 6;
    const int buf = k & 1;
    const int j0n = (j0 + 64) & (N_ - 1);

    // prefetch next K tile into regs
    half8 kp0, kp1;
    {
      const _Float16* ks = gbase + (size_t)(j0n + krow) * 64 + (kcb << 3);
      kp0 = *(const half8*)ks;
      kp1 = *(const half8*)(ks + 8);
    }
    // V fragments for this iter straight from global (L2)
    half8 vfr[8];
#pragma unroll
    for (int s = 0; s < 2; s++)
#pragma unroll
      for (int ct = 0; ct < 4; ct++)
        vfr[s * 4 + ct] = *(const half8*)(xbase + (size_t)(16 * ct + n16) * N_ +
                                          j0 + 32 * s + 8 * quad);

    // S = Q K^T for this wave's 16 rows (log2-scaled via prep)
    float4_t s_acc[4];
#pragma unroll
    for (int t = 0; t < 4; t++) s_acc[t] = (float4_t){0.f, 0.f, 0.f, 0.f};
    {
      const _Float16* ktb = smem + buf * 4096;
      __builtin_amdgcn_s_setprio(1);
#pragma unroll
      for (int s = 0; s < 2; s++)
#pragma unroll
        for (int t = 0; t < 4; t++) {
          half8 bf = *(const half8*)(ktb + (16 * t + n16) * 64 +
                                     (((4 * s + quad) ^ nlo) << 3));
          s_acc[t] = mfma16(qf[s], bf, s_acc[t]);
        }
      __builtin_amdgcn_s_setprio(0);
    }

    // online softmax (base-2) for this wave's rows; write P (swizzled) + alpha
    float alpha_r[4];
#pragma unroll
    for (int r = 0; r < 4; r++) {
      float v = fmaxf(fmaxf(s_acc[0][r], s_acc[1][r]),
                      fmaxf(s_acc[2][r], s_acc[3][r]));
      v = row_max16(v);                      // DPP reduce, no LDS traffic
      float mn = fmaxf(m_i[r], v);
      alpha_r[r] = EXP2(m_i[r] - mn);
      m_i[r] = mn;
    }
    _Float16* pb = smem + 8192 + buf * 4096;
#pragma unroll
    for (int r = 0; r < 4; r++) {
      float s0 = EXP2(s_acc[0][r] - m_i[r]);
      float s1 = EXP2(s_acc[1][r] - m_i[r]);
      float s2 = EXP2(s_acc[2][r] - m_i[r]);
      float s3 = EXP2(s_acc[3][r] - m_i[r]);
      float v = row_sum16(s0 + s1 + s2 + s3); // DPP reduce
      l_i[r] = l_i[r] * alpha_r[r] + v;
      const int row = wave * 16 + 4 * quad + r;
      const int rb  = row & 7;
      _Float16* pr = pb + row * 64 + nlo;
      pr[((nhi    ) ^ rb) << 3] = (_Float16)s0;
      pr[((nhi + 2) ^ rb) << 3] = (_Float16)s1;
      pr[((nhi + 4) ^ rb) << 3] = (_Float16)s2;
      pr[((nhi + 6) ^ rb) << 3] = (_Float16)s3;
    }
    if (n16 == 0) {
#pragma unroll
      for (int r = 0; r < 4; r++)
        alpha_lds[buf][wave * 16 + 4 * quad + r] = alpha_r[r];
    }
    // write prefetched K tile into other buffer
    {
      _Float16* kd = smem + (buf ^ 1) * 4096 + krow * 64;
      *(half8*)(kd + (((kcb    ) ^ krb) << 3)) = kp0;
      *(half8*)(kd + (((kcb + 1) ^ krb) << 3)) = kp1;
    }
    __syncthreads();

    // rescale O by alpha of each row (broadcast LDS reads)
#pragma unroll
    for (int ti = 0; ti < 4; ti++)
#pragma unroll
      for (int r = 0; r < 4; r++) {
        float al = alpha_lds[buf][ti * 16 + 4 * quad + r];
#pragma unroll
        for (int ct = 0; ct < 4; ct++) o_acc[ti * 4 + ct][r] *= al;
      }

    // O += P V  (P from shared LDS, V from regs)
    __builtin_amdgcn_s_setprio(1);
#pragma unroll
    for (int s = 0; s < 2; s++)
#pragma unroll
      for (int ti = 0; ti < 4; ti++) {
        half8 af = *(const half8*)(pb + (16 * ti + n16) * 64 +
                                   (((4 * s + quad) ^ nlo) << 3));
#pragma unroll
        for (int ct = 0; ct < 4; ct++)
          o_acc[ti * 4 + ct] = mfma16(af, vfr[s * 4 + ct], o_acc[ti * 4 + ct]);
      }
    __builtin_amdgcn_s_setprio(0);
  }

  // share 1/l across waves; barrier also guarantees every wave's PV LDS reads
  // are complete before smem is overwritten as the a-tile
  if (n16 == 0) {
#pragma unroll
    for (int r = 0; r < 4; r++)
      linv_lds[wave * 16 + 4 * quad + r] = 1.f / l_i[r];
  }
  __syncthreads();
  __builtin_amdgcn_sched_barrier(0);

  // normalize + write swizzled f16 a-tile [64 rows][256 cols] into smem[0,16384)
  // swizzle: 16B col-block cb stored at (cb ^ (row&7))
#pragma unroll
  for (int ti = 0; ti < 4; ti++)
#pragma unroll
    for (int r = 0; r < 4; r++) {
      const int row = ti * 16 + 4 * quad + r;
      const int rb  = row & 7;
      float il = linv_lds[row];
#pragma unroll
      for (int ct = 0; ct < 4; ct++) {
        const int cb = (wave << 3) + (ct << 1) + nhi;   // col>>3
        smem[row * 256 + ((cb ^ rb) << 3) + nlo] =
            (_Float16)(o_acc[ti * 4 + ct][r] * il);
      }
    }
  __syncthreads();
  __builtin_amdgcn_sched_barrier(0);

  // epilogue GEMM: wave w computes out[i0..i0+64)[64w..64w+64), K=256 from LDS
  float4_t ep[16];
#pragma unroll
  for (int t = 0; t < 16; t++) ep[t] = (float4_t){0.f, 0.f, 0.f, 0.f};
  for (int k0 = 0; k0 < 256; k0 += 32) {
    half8 af[4];
#pragma unroll
    for (int mi = 0; mi < 4; mi++) {
      const int row = mi * 16 + n16;
      const int kb  = ((k0 >> 3) + quad) ^ (row & 7);
      af[mi] = *(const half8*)(smem + row * 256 + (kb << 3));
    }
#pragma unroll
    for (int ct = 0; ct < 4; ct++) {
      half8 bf = *(const half8*)(whvt +
                  (size_t)(wave * 64 + ct * 16 + n16) * 256 + k0 + quad * 8);
#pragma unroll
      for (int mi = 0; mi < 4; mi++)
        ep[mi * 4 + ct] = mfma16(af[mi], bf, ep[mi * 4 + ct]);
    }
  }
  const float gm = gamma[0];
#pragma unroll
  for (int mi = 0; mi < 4; mi++)
#pragma unroll
    for (int r = 0; r < 4; r++) {
      size_t orow = (size_t)(b * N_ + i0 + mi * 16 + 4 * quad + r) * C_;
#pragma unroll
      for (int ct = 0; ct < 4; ct++) {
        size_t idx = orow + wave * 64 + ct * 16 + n16;
        out[idx] = gm * ep[mi * 4 + ct][r] + x[idx];
      }
    }
}

extern "C" void kernel_launch(void* const* d_in, const int* in_sizes, int n_in,
                              void* d_out, int out_size, void* d_ws, size_t ws_size,
                              hipStream_t stream) {
  const float* x     = (const float*)d_in[0];
  const float* Wf    = (const float*)d_in[1];
  const float* Wg    = (const float*)d_in[2];
  const float* Wh    = (const float*)d_in[3];
  const float* Wv    = (const float*)d_in[4];
  const float* gamma = (const float*)d_in[5];
  float* out = (float*)d_out;

  char* w = (char*)d_ws;
  _Float16* whvt = (_Float16*)(w);                                  // 128 KiB
  _Float16* wfgt = (_Float16*)(w + 131072);                         //  64 KiB
  _Float16* fb   = (_Float16*)(w + 196608);                         //   4 MiB
  _Float16* gb   = (_Float16*)(w + 196608 + 4194304);               //   4 MiB
  _Float16* xT   = (_Float16*)(w + 196608 + 2 * 4194304);           //  16 MiB

  hipLaunchKernelGGL(prep_kernel, dim3(384),    dim3(256), 0, stream,
                     Wh, Wv, Wf, Wg, whvt, wfgt);
  hipLaunchKernelGGL(fgt_kernel,  dim3(1024),   dim3(256), 0, stream,
                     x, wfgt, fb, gb, xT);
  hipLaunchKernelGGL(flash_kernel, dim3(8, 64), dim3(256), 0, stream,
                     fb, gb, xT, whvt, x, gamma, out);
}